// Round 14
// baseline (150.264 us; speedup 1.0000x reference)
//
#include <hip/hip_runtime.h>
#include <hip/hip_bf16.h>
#include <math.h>

#define B_    16
#define P_    25
#define D_SL_ 32
#define H_    320
#define W_    320
#define BP    400
#define KPIX  4096
#define FOUT  1280
#define HID   128
#define NG    3

#define M_PAD    512
#define KSPL     8
#define CH_STEPS 16          // 32-wide k-steps per k-chunk

#define CROP_BLOCKS 512      // fused_prep: blocks [0,512) crops, [512,1152) prep_w

typedef __attribute__((ext_vector_type(8))) short  bf16x8;
typedef __attribute__((ext_vector_type(8))) ushort u16x8;
typedef __attribute__((ext_vector_type(4))) float  f32x4;
typedef unsigned long long ull;

// ws byte offsets
#define OFF_APF  0ull            // A frag-panel: 8.4 MB
#define OFF_WPF  8388608ull      // W frag-panel: 21 MB
#define OFF_PART 29360128ull     // 8 x 400 x 1280 x 4 = 16.4 MB
#define OFF_BAR  67108864ull     // grid-barrier counter

// frag-panel index (16B units):
//  A: ((((st*4+mt)*2+wm)*2+hl)*4+mi)*4+kg)*16 + l16      (hl stride 256 idx16)
//  W: ((((st*8+nt)*2+wn)*2+hl)*5+ni)*4+kg)*16 + l16      (hl stride 320 idx16)

__device__ inline void split_bf16(float x, ushort& hi, ushort& lo) {
    __hip_bfloat16 h = __float2bfloat16(x);
    float hf = __bfloat162float(h);
    __hip_bfloat16 l = __float2bfloat16(x - hf);
    hi = *(ushort*)&h;
    lo = *(ushort*)&l;
}

// ---------------- fused prep (r13-proven, unchanged) ----------------
__global__ __launch_bounds__(256) void fused_prep(
    const float* __restrict__ images,
    const float* __restrict__ z_pred,
    const float* __restrict__ xy_pred,
    const float* __restrict__ Wf,
    ushort* __restrict__ APF, ushort* __restrict__ WPF)
{
    __shared__ float S[128][68];
    int t = threadIdx.x;

    if (blockIdx.x < CROP_BLOCKS) {
        int pt = blockIdx.x;
        int mt = pt >> 7, wmA = (pt >> 6) & 1, miA = (pt >> 4) & 3, l16A = pt & 15;

        if (pt >= BP) {
            u16x8 z8 = (u16x8)0;
            #pragma unroll
            for (int i = 0; i < 2; ++i) {
                int tau = t + i * 256;
                int st = tau >> 2, q = tau & 3;
                size_t base = (((((size_t)(st * 4 + mt) * 2 + wmA) * 2 + 0) * 4 + miA) * 4 + q) * 16 + l16A;
                *(u16x8*)(APF + base * 8) = z8;
                *(u16x8*)(APF + (base + 256) * 8) = z8;
            }
            return;
        }
        int b = pt / P_;
        int z = (int)rintf(z_pred[pt] - 1.0f);
        z = min(max(z, 0), D_SL_ - 1);
        int x = (int)rintf(4.0f * xy_pred[pt * 2 + 0]);
        int y = (int)rintf(4.0f * xy_pred[pt * 2 + 1]);
        x = min(max(x, 0), W_ - 1);
        y = min(max(y, 0), H_ - 1);
        const float* img = images + (size_t)(b * D_SL_ + z) * (H_ * W_);

        #pragma unroll
        for (int i = 0; i < 16; ++i) {
            int idx = t + i * 256;
            int r = idx >> 6, c = idx & 63;
            int iy = y - 32 + r, ix = x - 32 + c;
            float v = 0.0f;
            if ((unsigned)iy < (unsigned)H_ && (unsigned)ix < (unsigned)W_)
                v = img[iy * W_ + ix];
            S[r][c] = v;
        }
        __syncthreads();

        #pragma unroll
        for (int i = 0; i < 2; ++i) {
            int tau = t + i * 256;
            int st = tau >> 2, q = tau & 3;
            int r = st >> 1, cb = (st & 1) * 32 + q * 8;
            u16x8 vh, vl;
            #pragma unroll
            for (int e = 0; e < 8; ++e) {
                ushort hi, lo;
                split_bf16(S[r][cb + e], hi, lo);
                vh[e] = hi; vl[e] = lo;
            }
            size_t base = (((((size_t)(st * 4 + mt) * 2 + wmA) * 2 + 0) * 4 + miA) * 4 + q) * 16 + l16A;
            *(u16x8*)(APF + base * 8) = vh;
            *(u16x8*)(APF + (base + 256) * 8) = vl;
        }
        return;
    }

    // ---- W-prep: Wsum -> frag panel (8 nt x 160) ----
    int wb = blockIdx.x - CROP_BLOCKS;   // 0..639
    int k0 = (wb & 31) * 128;
    int n0w = (wb >> 5) * 64;
    #pragma unroll
    for (int p = 0; p < 8; ++p) {
        int kl = p * 16 + (t >> 4);
        int nq = (t & 15) * 4;
        const float* base = Wf + (size_t)(k0 + kl) * FOUT + n0w + nq;
        float4 a = *(const float4*)base;
        float4 b = *(const float4*)(base + (size_t)KPIX * FOUT);
        float4 c = *(const float4*)(base + (size_t)2 * KPIX * FOUT);
        *(float4*)&S[kl][nq] = make_float4(a.x + b.x + c.x, a.y + b.y + c.y,
                                           a.z + b.z + c.z, a.w + b.w + c.w);
    }
    __syncthreads();
    int stepl = t >> 6;
    int nl = t & 63;
    int gstep = (wb & 31) * 4 + stepl;
    int n = n0w + nl;
    int nt = n / 160;
    int rem = n - nt * 160;
    int wnB = rem / 80;
    int rem2 = rem - wnB * 80;
    int niB = rem2 >> 4, l16B = rem2 & 15;
    ushort hi[32], lo[32];
    #pragma unroll
    for (int j = 0; j < 32; ++j) {
        float v = S[stepl * 32 + j][nl];
        split_bf16(v, hi[j], lo[j]);
    }
    #pragma unroll
    for (int q = 0; q < 4; ++q) {
        u16x8 vh, vl;
        #pragma unroll
        for (int e = 0; e < 8; ++e) { vh[e] = hi[q * 8 + e]; vl[e] = lo[q * 8 + e]; }
        size_t inner = ((((size_t)(gstep * 8 + nt)) * 2 + wnB) * 2 + 0) * 5 + niB;
        size_t base = (inner * 4 + q) * 16 + l16B;
        *(u16x8*)(WPF + base * 8) = vh;
        *(u16x8*)(WPF + (base + 320) * 8) = vl;
    }
}

// grid-wide barrier: 256 blocks x 1/CU -> all resident (r8-proven semantics)
__device__ inline void gbar(unsigned* ctr, unsigned target) {
    __threadfence();
    __syncthreads();
    if (threadIdx.x == 0) {
        atomicAdd(ctr, 1u);
        while (__hip_atomic_load(ctr, __ATOMIC_RELAXED, __HIP_MEMORY_SCOPE_AGENT) < target)
            __builtin_amdgcn_s_sleep(2);
    }
    __syncthreads();
    __threadfence();
}

// ---------------- fused GEMM (r13-proven) + grid barrier + MLP/loss ----------------
__global__ __launch_bounds__(256) void gemm_mlp(
    const ushort* __restrict__ APF, const ushort* __restrict__ WPF,
    const float* __restrict__ bfeat,
    const float* __restrict__ W1, const float* __restrict__ b1,
    const float* __restrict__ W2, const float* __restrict__ b2,
    const int* __restrict__ grade,
    float* __restrict__ part,
    float* __restrict__ probs, float* out0, unsigned* bar)
{
    __shared__ float sf[4][FOUT];       // 20 KB (phase B)
    __shared__ float shp[2][4][HID];    // 4 KB
    __shared__ float sh[4][HID];
    __shared__ float sl[4][NG];
    __shared__ float sden[256];

    int t = threadIdx.x;
    int id = blockIdx.x;

    // ---------- phase A: GEMM (byte-identical r13 math) ----------
    {
        int kz = id & 7;
        int rr_ = id >> 3;
        int nt = rr_ & 7;
        int mt = rr_ >> 3;
        int stepbase = kz * CH_STEPS;

        int w = t >> 6, l = t & 63;
        int wm = w & 1, wn = w >> 1;
        int l16 = l & 15, kg = l >> 4;

        f32x4 acc[4][5];
        #pragma unroll
        for (int i = 0; i < 4; ++i)
            #pragma unroll
            for (int j = 0; j < 5; ++j) acc[i][j] = (f32x4){0.f, 0.f, 0.f, 0.f};

        size_t abase0 = ((((size_t)mt * 2 + wm) * 2) * 16 + kg) * 16 + l16;
        abase0 *= 8;
        size_t bbase0 = ((((size_t)nt * 2 + wn) * 40) + kg) * 16 + l16;
        bbase0 *= 8;

        for (int s = 0; s < CH_STEPS; ++s) {
            int st = stepbase + s;
            const ushort* ap = APF + abase0 + (size_t)st * 32768;
            const ushort* bp = WPF + bbase0 + (size_t)st * 81920;

            bf16x8 ah[4], al[4], bh[5], bl[5];
            #pragma unroll
            for (int mi = 0; mi < 4; ++mi) {
                ah[mi] = *(const bf16x8*)(ap + (size_t)mi * 512);
                al[mi] = *(const bf16x8*)(ap + 2048 + (size_t)mi * 512);
            }
            #pragma unroll
            for (int ni = 0; ni < 5; ++ni) {
                bh[ni] = *(const bf16x8*)(bp + (size_t)ni * 512);
                bl[ni] = *(const bf16x8*)(bp + 2560 + (size_t)ni * 512);
            }
            #pragma unroll
            for (int mi = 0; mi < 4; ++mi)
                #pragma unroll
                for (int ni = 0; ni < 5; ++ni) {
                    acc[mi][ni] = __builtin_amdgcn_mfma_f32_16x16x32_bf16(ah[mi], bh[ni], acc[mi][ni], 0, 0, 0);
                    acc[mi][ni] = __builtin_amdgcn_mfma_f32_16x16x32_bf16(ah[mi], bl[ni], acc[mi][ni], 0, 0, 0);
                    acc[mi][ni] = __builtin_amdgcn_mfma_f32_16x16x32_bf16(al[mi], bh[ni], acc[mi][ni], 0, 0, 0);
                }
        }

        int m0 = mt * 128, n0 = nt * 160;
        #pragma unroll
        for (int mi = 0; mi < 4; ++mi)
            #pragma unroll
            for (int ni = 0; ni < 5; ++ni)
                #pragma unroll
                for (int r = 0; r < 4; ++r) {
                    int m = m0 + wm * 64 + mi * 16 + kg * 4 + r;
                    if (m < BP) {
                        int n = n0 + wn * 80 + ni * 16 + l16;
                        part[((size_t)kz * BP + m) * FOUT + n] = acc[mi][ni][r];
                    }
                }
    }

    gbar(bar, 256);

    // ---------- phase B: MLP + softmax + loss (blocks 0..99, 4 rows each) ----------
    if (id >= 100) return;
    int r0 = id * 4;

    float dwt = 0.0f;
    for (int p = t; p < BP; p += 256) {
        int g = grade[p];
        dwt += (g == 0) ? 1.0f : (g == 1 ? 2.0f : 4.0f);
    }
    sden[t] = dwt;

    for (int i = t; i < 4 * FOUT; i += 256) {
        int r = i / FOUT, c = i - r * FOUT;
        size_t base = (size_t)(r0 + r) * FOUT + c;
        float v = bfeat[c];
        #pragma unroll
        for (int kzi = 0; kzi < KSPL; ++kzi)
            v += part[(size_t)kzi * BP * FOUT + base];
        sf[r][c] = v;
    }
    __syncthreads();
    for (int s = 128; s > 0; s >>= 1) {
        if (t < s) sden[t] += sden[t + s];
        __syncthreads();
    }
    float den = sden[0];

    {
        int kh = t >> 7, j = t & 127;       // K halves of 640
        float a0 = (kh == 0) ? b1[j] : 0.0f, a1 = 0.0f, a2 = 0.0f, a3 = 0.0f;
        const float* wp = W1 + (size_t)(kh * 640) * HID + j;
        const float* s0 = &sf[0][kh * 640];
        const float* s1 = &sf[1][kh * 640];
        const float* s2 = &sf[2][kh * 640];
        const float* s3 = &sf[3][kh * 640];
        #pragma unroll 8
        for (int k = 0; k < 640; ++k) {
            float wv = wp[(size_t)k * HID];
            a0 = fmaf(s0[k], wv, a0);
            a1 = fmaf(s1[k], wv, a1);
            a2 = fmaf(s2[k], wv, a2);
            a3 = fmaf(s3[k], wv, a3);
        }
        shp[kh][0][j] = a0;
        shp[kh][1][j] = a1;
        shp[kh][2][j] = a2;
        shp[kh][3][j] = a3;
    }
    __syncthreads();
    #pragma unroll
    for (int i = t; i < 4 * HID; i += 256) {
        int rr = i >> 7, jj = i & 127;
        sh[rr][jj] = fmaxf(shp[0][rr][jj] + shp[1][rr][jj], 0.0f);
    }
    __syncthreads();
    if (t < 12) {
        int rr = t / 3, c = t - rr * 3;
        float a = b2[c];
        #pragma unroll 16
        for (int k = 0; k < HID; ++k) a = fmaf(sh[rr][k], W2[k * NG + c], a);
        sl[rr][c] = a;
    }
    __syncthreads();
    if (t < 4) {
        float l0 = sl[t][0], l1 = sl[t][1], l2 = sl[t][2];
        float m = fmaxf(l0, fmaxf(l1, l2));
        float e0 = expf(l0 - m), e1 = expf(l1 - m), e2 = expf(l2 - m);
        float inv = 1.0f / (e0 + e1 + e2);
        int row = r0 + t;
        probs[row * NG + 0] = e0 * inv;
        probs[row * NG + 1] = e1 * inv;
        probs[row * NG + 2] = e2 * inv;

        int g = grade[row];
        float lv = (g == 0) ? l0 : (g == 1 ? l1 : l2);
        lv = fminf(fmaxf(lv, 1e-5f), 1.0f - 1e-5f);
        float wt = (g == 0) ? 1.0f : (g == 1 ? 2.0f : 4.0f);
        atomicAdd(out0, -(wt * logf(lv)) / den);
    }
}

// ---------------- launch ----------------
extern "C" void kernel_launch(void* const* d_in, const int* in_sizes, int n_in,
                              void* d_out, int out_size, void* d_ws, size_t ws_size,
                              hipStream_t stream) {
    const float* images  = (const float*)d_in[0];
    const float* z_pred  = (const float*)d_in[1];
    const float* xy_pred = (const float*)d_in[2];
    const int*   grade   = (const int*)d_in[3];
    const float* W_feat  = (const float*)d_in[4];
    const float* b_feat  = (const float*)d_in[5];
    const float* W1      = (const float*)d_in[6];
    const float* b1      = (const float*)d_in[7];
    const float* W2      = (const float*)d_in[8];
    const float* b2      = (const float*)d_in[9];

    float* out = (float*)d_out;
    char* w = (char*)d_ws;
    ushort* APF  = (ushort*)(w + OFF_APF);
    ushort* WPF  = (ushort*)(w + OFF_WPF);
    float*  part = (float*)(w + OFF_PART);
    unsigned* bar = (unsigned*)(w + OFF_BAR);

    hipMemsetAsync(bar, 0, 64, stream);
    hipMemsetAsync(out, 0, 4, stream);
    fused_prep<<<CROP_BLOCKS + 640, 256, 0, stream>>>(images, z_pred, xy_pred, W_feat,
                                                      APF, WPF);
    gemm_mlp<<<256, 256, 0, stream>>>(APF, WPF, b_feat, W1, b1, W2, b2, grade,
                                      part, out + 1, out, bar);
}

// Round 15
// 71.235 us; speedup vs baseline: 2.1094x; 2.1094x over previous
//
#include <hip/hip_runtime.h>
#include <hip/hip_bf16.h>
#include <math.h>

#define B_    16
#define P_    25
#define D_SL_ 32
#define H_    320
#define W_    320
#define BP    400
#define KPIX  4096
#define FOUT  1280
#define HID   128
#define NG    3

#define M_PAD    512
#define KSPL     8
#define CH_STEPS 16          // 32-wide k-steps per k-chunk

#define CROP_BLOCKS 512      // fused_prep: blocks [0,512) crops, [512,1152) prep_w

typedef __attribute__((ext_vector_type(8))) short  bf16x8;
typedef __attribute__((ext_vector_type(8))) ushort u16x8;
typedef __attribute__((ext_vector_type(4))) float  f32x4;
typedef unsigned long long ull;

// ws byte offsets
#define OFF_APF  0ull            // A frag-panel (hi+lo): 8.4 MB
#define OFF_WPF  8388608ull      // W frag-panel (hi only): 10.5 MB
#define OFF_PART 29360128ull     // 8 x 400 x 1280 x 4 = 16.4 MB

// frag-panel index (16B units):
//  A: ((((st*4+mt)*2+wm)*2+hl)*4+mi)*4+kg)*16 + l16      (hl stride 256 idx16)  [r12-proven]
//  W: (((st*10+nt)*2+wn)*4+ni)*4+kg)*16 + l16            (hi only; st stride 5120 idx16)

__device__ inline void split_bf16(float x, ushort& hi, ushort& lo) {
    __hip_bfloat16 h = __float2bfloat16(x);
    float hf = __bfloat162float(h);
    __hip_bfloat16 l = __float2bfloat16(x - hf);
    hi = *(ushort*)&h;
    lo = *(ushort*)&l;
}

// ---------------- fused prep: crops->A-fragpanel (hi+lo) + Wsum->W-fragpanel (hi) ----
__global__ __launch_bounds__(256) void fused_prep(
    const float* __restrict__ images,
    const float* __restrict__ z_pred,
    const float* __restrict__ xy_pred,
    const float* __restrict__ Wf,
    ushort* __restrict__ APF, ushort* __restrict__ WPF)
{
    __shared__ float S[128][68];
    int t = threadIdx.x;

    if (blockIdx.x < CROP_BLOCKS) {
        int pt = blockIdx.x;
        int mt = pt >> 7, wmA = (pt >> 6) & 1, miA = (pt >> 4) & 3, l16A = pt & 15;

        if (pt >= BP) {
            u16x8 z8 = (u16x8)0;
            #pragma unroll
            for (int i = 0; i < 2; ++i) {
                int tau = t + i * 256;
                int st = tau >> 2, q = tau & 3;
                size_t base = (((((size_t)(st * 4 + mt) * 2 + wmA) * 2 + 0) * 4 + miA) * 4 + q) * 16 + l16A;
                *(u16x8*)(APF + base * 8) = z8;
                *(u16x8*)(APF + (base + 256) * 8) = z8;
            }
            return;
        }
        int b = pt / P_;
        int z = (int)rintf(z_pred[pt] - 1.0f);
        z = min(max(z, 0), D_SL_ - 1);
        int x = (int)rintf(4.0f * xy_pred[pt * 2 + 0]);
        int y = (int)rintf(4.0f * xy_pred[pt * 2 + 1]);
        x = min(max(x, 0), W_ - 1);
        y = min(max(y, 0), H_ - 1);
        const float* img = images + (size_t)(b * D_SL_ + z) * (H_ * W_);

        #pragma unroll
        for (int i = 0; i < 16; ++i) {
            int idx = t + i * 256;
            int r = idx >> 6, c = idx & 63;
            int iy = y - 32 + r, ix = x - 32 + c;
            float v = 0.0f;
            if ((unsigned)iy < (unsigned)H_ && (unsigned)ix < (unsigned)W_)
                v = img[iy * W_ + ix];
            S[r][c] = v;
        }
        __syncthreads();

        #pragma unroll
        for (int i = 0; i < 2; ++i) {
            int tau = t + i * 256;
            int st = tau >> 2, q = tau & 3;
            int r = st >> 1, cb = (st & 1) * 32 + q * 8;
            u16x8 vh, vl;
            #pragma unroll
            for (int e = 0; e < 8; ++e) {
                ushort hi, lo;
                split_bf16(S[r][cb + e], hi, lo);
                vh[e] = hi; vl[e] = lo;
            }
            size_t base = (((((size_t)(st * 4 + mt) * 2 + wmA) * 2 + 0) * 4 + miA) * 4 + q) * 16 + l16A;
            *(u16x8*)(APF + base * 8) = vh;
            *(u16x8*)(APF + (base + 256) * 8) = vl;
        }
        return;
    }

    // ---- W-prep: Wsum -> frag panel, hi only ----
    int wb = blockIdx.x - CROP_BLOCKS;   // 0..639
    int k0 = (wb & 31) * 128;
    int n0w = (wb >> 5) * 64;
    #pragma unroll
    for (int p = 0; p < 8; ++p) {
        int kl = p * 16 + (t >> 4);
        int nq = (t & 15) * 4;
        const float* base = Wf + (size_t)(k0 + kl) * FOUT + n0w + nq;
        float4 a = *(const float4*)base;
        float4 b = *(const float4*)(base + (size_t)KPIX * FOUT);
        float4 c = *(const float4*)(base + (size_t)2 * KPIX * FOUT);
        *(float4*)&S[kl][nq] = make_float4(a.x + b.x + c.x, a.y + b.y + c.y,
                                           a.z + b.z + c.z, a.w + b.w + c.w);
    }
    __syncthreads();
    int stepl = t >> 6;
    int nl = t & 63;
    int gstep = (wb & 31) * 4 + stepl;
    int n = n0w + nl;
    int nt = n >> 7, wnB = (n >> 6) & 1, niB = (n >> 4) & 3, l16B = n & 15;
    ushort hi[32];
    #pragma unroll
    for (int j = 0; j < 32; ++j) {
        __hip_bfloat16 h = __float2bfloat16(S[stepl * 32 + j][nl]);
        hi[j] = *(ushort*)&h;
    }
    #pragma unroll
    for (int q = 0; q < 4; ++q) {
        u16x8 vh;
        #pragma unroll
        for (int e = 0; e < 8; ++e) vh[e] = hi[q * 8 + e];
        size_t inner = (((size_t)(gstep * 10 + nt)) * 2 + wnB) * 4 + niB;
        size_t base = (inner * 4 + q) * 16 + l16B;
        *(u16x8*)(WPF + base * 8) = vh;
    }
}

// ---------------- MFMA GEMM v6: LDS-free, W hi-only (2 MFMA per frag pair) -------
// 320 blocks: id = kz + 8*rr; rr -> (mt, nt). kz = id&7 -> XCD pinning.
__global__ __launch_bounds__(256) void gemm_mfma(
    const ushort* __restrict__ APF, const ushort* __restrict__ WPF,
    float* __restrict__ part, float* __restrict__ out0)
{
    int t = threadIdx.x;
    int id = blockIdx.x;
    int kz = id & 7;
    int rr_ = id >> 3;               // 0..39
    int nt = rr_ % 10;
    int mt = rr_ / 10;
    int stepbase = kz * CH_STEPS;

    if (id == 0 && t == 0) out0[0] = 0.0f;

    int w = t >> 6, l = t & 63;
    int wm = w & 1, wn = w >> 1;
    int l16 = l & 15, kg = l >> 4;

    f32x4 acc[4][4];
    #pragma unroll
    for (int i = 0; i < 4; ++i)
        #pragma unroll
        for (int j = 0; j < 4; ++j) acc[i][j] = (f32x4){0.f, 0.f, 0.f, 0.f};

    // A base (us): strides kg 128, mi 512, hl 2048, st 32768  [r12-proven]
    size_t abase0 = ((((size_t)mt * 2 + wm) * 2) * 16 + kg) * 16 + l16;
    abase0 *= 8;
    // W base (us): idx16 = (((nt*2+wn)*4+ni)*4+kg)*16+l16 -> strides ni 512, st 40960
    size_t bbase0 = (((size_t)nt * 2 + wn) * 16 + kg) * 16 + l16;
    bbase0 *= 8;

    for (int s = 0; s < CH_STEPS; ++s) {
        int st = stepbase + s;
        const ushort* ap = APF + abase0 + (size_t)st * 32768;
        const ushort* bp = WPF + bbase0 + (size_t)st * 40960;

        bf16x8 ah[4], al[4], bh[4];
        #pragma unroll
        for (int mi = 0; mi < 4; ++mi) {
            ah[mi] = *(const bf16x8*)(ap + (size_t)mi * 512);
            al[mi] = *(const bf16x8*)(ap + 2048 + (size_t)mi * 512);
        }
        #pragma unroll
        for (int ni = 0; ni < 4; ++ni)
            bh[ni] = *(const bf16x8*)(bp + (size_t)ni * 512);
        #pragma unroll
        for (int mi = 0; mi < 4; ++mi)
            #pragma unroll
            for (int ni = 0; ni < 4; ++ni) {
                acc[mi][ni] = __builtin_amdgcn_mfma_f32_16x16x32_bf16(ah[mi], bh[ni], acc[mi][ni], 0, 0, 0);
                acc[mi][ni] = __builtin_amdgcn_mfma_f32_16x16x32_bf16(al[mi], bh[ni], acc[mi][ni], 0, 0, 0);
            }
    }

    // epilogue (proven): row = kg*4 + reg, col = l16
    int m0 = mt * 128, n0 = nt * 128;
    #pragma unroll
    for (int mi = 0; mi < 4; ++mi)
        #pragma unroll
        for (int ni = 0; ni < 4; ++ni)
            #pragma unroll
            for (int r = 0; r < 4; ++r) {
                int m = m0 + wm * 64 + mi * 16 + kg * 4 + r;
                if (m < BP) {
                    int n = n0 + wn * 64 + ni * 16 + l16;
                    part[((size_t)kz * BP + m) * FOUT + n] = acc[mi][ni][r];
                }
            }
}

// ---------------- MLP + softmax + fused loss (r9-proven, unchanged) ----------------
__global__ __launch_bounds__(512) void mlp2x_loss(
    const float* __restrict__ part,
    const float* __restrict__ bfeat,
    const float* __restrict__ W1, const float* __restrict__ b1,
    const float* __restrict__ W2, const float* __restrict__ b2,
    const int* __restrict__ grade,
    float* __restrict__ probs, float* __restrict__ out0)
{
    __shared__ float sf[2][FOUT];
    __shared__ float shp[4][2][HID];
    __shared__ float sh[2][HID];
    __shared__ float sl[2][NG];
    __shared__ float sden[512];
    int r0 = blockIdx.x * 2;
    int t = threadIdx.x;

    float dwt = 0.0f;
    if (t < BP) {
        int g = grade[t];
        dwt = (g == 0) ? 1.0f : (g == 1 ? 2.0f : 4.0f);
    }
    sden[t] = dwt;

    for (int i = t; i < 2 * FOUT; i += 512) {
        int r = i / FOUT, c = i - r * FOUT;
        size_t base = (size_t)(r0 + r) * FOUT + c;
        float v = bfeat[c];
        #pragma unroll
        for (int kzi = 0; kzi < KSPL; ++kzi)
            v += part[(size_t)kzi * BP * FOUT + base];
        sf[r][c] = v;
    }
    __syncthreads();
    for (int s = 256; s > 0; s >>= 1) {
        if (t < s) sden[t] += sden[t + s];
        __syncthreads();
    }
    float den = sden[0];

    {
        int kq = t >> 7, j = t & 127;
        float a0 = (kq == 0) ? b1[j] : 0.0f, a1 = 0.0f;
        const float* wp = W1 + (size_t)(kq * 320) * HID + j;
        const float* s0 = &sf[0][kq * 320];
        const float* s1 = &sf[1][kq * 320];
        #pragma unroll 8
        for (int k = 0; k < 320; ++k) {
            float wv = wp[(size_t)k * HID];
            a0 = fmaf(s0[k], wv, a0);
            a1 = fmaf(s1[k], wv, a1);
        }
        shp[kq][0][j] = a0;
        shp[kq][1][j] = a1;
    }
    __syncthreads();
    if (t < 256) {
        int rr = t >> 7, j = t & 127;
        sh[rr][j] = fmaxf(shp[0][rr][j] + shp[1][rr][j] + shp[2][rr][j] + shp[3][rr][j], 0.0f);
    }
    __syncthreads();
    if (t < 6) {
        int rr = t / 3, c = t - rr * 3;
        float a = b2[c];
        #pragma unroll 16
        for (int k = 0; k < HID; ++k) a = fmaf(sh[rr][k], W2[k * NG + c], a);
        sl[rr][c] = a;
    }
    __syncthreads();
    if (t < 2) {
        float l0 = sl[t][0], l1 = sl[t][1], l2 = sl[t][2];
        float m = fmaxf(l0, fmaxf(l1, l2));
        float e0 = expf(l0 - m), e1 = expf(l1 - m), e2 = expf(l2 - m);
        float inv = 1.0f / (e0 + e1 + e2);
        int row = r0 + t;
        probs[row * NG + 0] = e0 * inv;
        probs[row * NG + 1] = e1 * inv;
        probs[row * NG + 2] = e2 * inv;

        int g = grade[row];
        float lv = (g == 0) ? l0 : (g == 1 ? l1 : l2);
        lv = fminf(fmaxf(lv, 1e-5f), 1.0f - 1e-5f);
        float wt = (g == 0) ? 1.0f : (g == 1 ? 2.0f : 4.0f);
        atomicAdd(out0, -(wt * logf(lv)) / den);
    }
}

// ---------------- launch ----------------
extern "C" void kernel_launch(void* const* d_in, const int* in_sizes, int n_in,
                              void* d_out, int out_size, void* d_ws, size_t ws_size,
                              hipStream_t stream) {
    const float* images  = (const float*)d_in[0];
    const float* z_pred  = (const float*)d_in[1];
    const float* xy_pred = (const float*)d_in[2];
    const int*   grade   = (const int*)d_in[3];
    const float* W_feat  = (const float*)d_in[4];
    const float* b_feat  = (const float*)d_in[5];
    const float* W1      = (const float*)d_in[6];
    const float* b1      = (const float*)d_in[7];
    const float* W2      = (const float*)d_in[8];
    const float* b2      = (const float*)d_in[9];

    float* out = (float*)d_out;
    char* w = (char*)d_ws;
    ushort* APF  = (ushort*)(w + OFF_APF);
    ushort* WPF  = (ushort*)(w + OFF_WPF);
    float*  part = (float*)(w + OFF_PART);

    fused_prep<<<CROP_BLOCKS + 640, 256, 0, stream>>>(images, z_pred, xy_pred, W_feat,
                                                      APF, WPF);
    gemm_mfma<<<10 * 4 * KSPL, 256, 0, stream>>>(APF, WPF, part, out);
    mlp2x_loss<<<BP / 2, 512, 0, stream>>>(part, b_feat, W1, b1, W2, b2, grade, out + 1, out);
}

// Round 16
// 69.610 us; speedup vs baseline: 2.1586x; 1.0233x over previous
//
#include <hip/hip_runtime.h>
#include <hip/hip_bf16.h>
#include <math.h>

#define B_    16
#define P_    25
#define D_SL_ 32
#define H_    320
#define W_    320
#define BP    400
#define KPIX  4096
#define FOUT  1280
#define HID   128
#define NG    3

#define M_PAD    512
#define KSPL     8
#define CH_STEPS 16          // 32-wide k-steps per k-chunk

#define CROP_BLOCKS 512      // fused_prep: blocks [0,512) crops, [512,1152) prep_w

typedef __attribute__((ext_vector_type(8))) short  bf16x8;
typedef __attribute__((ext_vector_type(8))) ushort u16x8;
typedef __attribute__((ext_vector_type(4))) float  f32x4;
typedef unsigned long long ull;

// ws byte offsets
#define OFF_APF  0ull            // A frag-panel: 128 st x 4 mt x 16KB = 8.4 MB
#define OFF_WPF  8388608ull      // W frag-panel: 128 st x 10 nt x 16KB = 21 MB
#define OFF_PART 29360128ull     // 8 x 400 x 1280 x 4 = 16.4 MB

// frag-panel index (16B units):
//  A: ((((st*4+mt)*2+wm)*2+hl)*4+mi)*4+kg)*16 + l16   (hl stride = 256 idx16)
//  W: ((((st*10+nt)*2+wn)*2+hl)*4+ni)*4+kg)*16 + l16

__device__ inline void split_bf16(float x, ushort& hi, ushort& lo) {
    __hip_bfloat16 h = __float2bfloat16(x);
    float hf = __bfloat162float(h);
    __hip_bfloat16 l = __float2bfloat16(x - hf);
    hi = *(ushort*)&h;
    lo = *(ushort*)&l;
}

// ---------------- fused prep: crops->A-fragpanel + Wsum->W-fragpanel ----------------
__global__ __launch_bounds__(256) void fused_prep(
    const float* __restrict__ images,
    const float* __restrict__ z_pred,
    const float* __restrict__ xy_pred,
    const float* __restrict__ Wf,
    ushort* __restrict__ APF, ushort* __restrict__ WPF)
{
    __shared__ float S[128][68];
    int t = threadIdx.x;

    if (blockIdx.x < CROP_BLOCKS) {
        int pt = blockIdx.x;
        int mt = pt >> 7, wmA = (pt >> 6) & 1, miA = (pt >> 4) & 3, l16A = pt & 15;

        if (pt >= BP) {
            u16x8 z8 = (u16x8)0;
            #pragma unroll
            for (int i = 0; i < 2; ++i) {
                int tau = t + i * 256;
                int st = tau >> 2, q = tau & 3;
                size_t base = (((((size_t)(st * 4 + mt) * 2 + wmA) * 2 + 0) * 4 + miA) * 4 + q) * 16 + l16A;
                *(u16x8*)(APF + base * 8) = z8;             // hi (hl=0)
                *(u16x8*)(APF + (base + 256) * 8) = z8;     // lo (hl=1)
            }
            return;
        }
        int b = pt / P_;
        int z = (int)rintf(z_pred[pt] - 1.0f);
        z = min(max(z, 0), D_SL_ - 1);
        int x = (int)rintf(4.0f * xy_pred[pt * 2 + 0]);
        int y = (int)rintf(4.0f * xy_pred[pt * 2 + 1]);
        x = min(max(x, 0), W_ - 1);
        y = min(max(y, 0), H_ - 1);
        const float* img = images + (size_t)(b * D_SL_ + z) * (H_ * W_);

        #pragma unroll
        for (int i = 0; i < 16; ++i) {
            int idx = t + i * 256;
            int r = idx >> 6, c = idx & 63;
            int iy = y - 32 + r, ix = x - 32 + c;
            float v = 0.0f;
            if ((unsigned)iy < (unsigned)H_ && (unsigned)ix < (unsigned)W_)
                v = img[iy * W_ + ix];
            S[r][c] = v;
        }
        __syncthreads();

        #pragma unroll
        for (int i = 0; i < 2; ++i) {
            int tau = t + i * 256;
            int st = tau >> 2, q = tau & 3;
            int r = st >> 1, cb = (st & 1) * 32 + q * 8;
            u16x8 vh, vl;
            #pragma unroll
            for (int e = 0; e < 8; ++e) {
                ushort hi, lo;
                split_bf16(S[r][cb + e], hi, lo);
                vh[e] = hi; vl[e] = lo;
            }
            size_t base = (((((size_t)(st * 4 + mt) * 2 + wmA) * 2 + 0) * 4 + miA) * 4 + q) * 16 + l16A;
            *(u16x8*)(APF + base * 8) = vh;
            *(u16x8*)(APF + (base + 256) * 8) = vl;
        }
        return;
    }

    // ---- W-prep: Wsum -> frag panel ----
    int wb = blockIdx.x - CROP_BLOCKS;   // 0..639
    int k0 = (wb & 31) * 128;
    int n0w = (wb >> 5) * 64;
    #pragma unroll
    for (int p = 0; p < 8; ++p) {
        int kl = p * 16 + (t >> 4);
        int nq = (t & 15) * 4;
        const float* base = Wf + (size_t)(k0 + kl) * FOUT + n0w + nq;
        float4 a = *(const float4*)base;
        float4 b = *(const float4*)(base + (size_t)KPIX * FOUT);
        float4 c = *(const float4*)(base + (size_t)2 * KPIX * FOUT);
        *(float4*)&S[kl][nq] = make_float4(a.x + b.x + c.x, a.y + b.y + c.y,
                                           a.z + b.z + c.z, a.w + b.w + c.w);
    }
    __syncthreads();
    int stepl = t >> 6;
    int nl = t & 63;
    int gstep = (wb & 31) * 4 + stepl;
    int n = n0w + nl;
    int nt = n >> 7, wnB = (n >> 6) & 1, niB = (n >> 4) & 3, l16B = n & 15;
    ushort hi[32], lo[32];
    #pragma unroll
    for (int j = 0; j < 32; ++j) {
        float v = S[stepl * 32 + j][nl];
        split_bf16(v, hi[j], lo[j]);
    }
    #pragma unroll
    for (int q = 0; q < 4; ++q) {
        u16x8 vh, vl;
        #pragma unroll
        for (int e = 0; e < 8; ++e) { vh[e] = hi[q * 8 + e]; vl[e] = lo[q * 8 + e]; }
        size_t base = (((((size_t)(gstep * 10 + nt) * 2 + wnB) * 2 + 0) * 4 + niB) * 4 + q) * 16 + l16B;
        *(u16x8*)(WPF + base * 8) = vh;
        *(u16x8*)(WPF + (base + 256) * 8) = vl;
    }
}

// ---------------- MFMA GEMM v4: LDS-free, frag-panel direct loads ----------------
// 320 blocks: id = kz + 8*rr; rr -> (mt, nt). kz = id&7 -> XCD pinning.
__global__ __launch_bounds__(256) void gemm_mfma(
    const ushort* __restrict__ APF, const ushort* __restrict__ WPF,
    float* __restrict__ part, float* __restrict__ out0)
{
    int t = threadIdx.x;
    int id = blockIdx.x;
    int kz = id & 7;
    int rr_ = id >> 3;               // 0..39
    int nt = rr_ % 10;
    int mt = rr_ / 10;
    int stepbase = kz * CH_STEPS;

    if (id == 0 && t == 0) out0[0] = 0.0f;

    int w = t >> 6, l = t & 63;
    int wm = w & 1, wn = w >> 1;
    int l16 = l & 15, kg = l >> 4;

    f32x4 acc[4][4];
    #pragma unroll
    for (int i = 0; i < 4; ++i)
        #pragma unroll
        for (int j = 0; j < 4; ++j) acc[i][j] = (f32x4){0.f, 0.f, 0.f, 0.f};

    // per-lane base addresses (ushort units); strides: kg 128, mi/ni 512, hl 2048
    size_t abase0 = ((((size_t)mt * 2 + wm) * 2) * 16 + kg) * 16 + l16;
    abase0 *= 8;
    size_t bbase0 = ((((size_t)nt * 2 + wn) * 2) * 16 + kg) * 16 + l16;
    bbase0 *= 8;

    for (int s = 0; s < CH_STEPS; ++s) {
        int st = stepbase + s;
        const ushort* ap = APF + abase0 + (size_t)st * 32768;   // A st stride: 4096 idx16
        const ushort* bp = WPF + bbase0 + (size_t)st * 81920;   // W st stride: 10240 idx16

        bf16x8 ah[4], al[4], bh[4], bl[4];
        #pragma unroll
        for (int mi = 0; mi < 4; ++mi) {
            ah[mi] = *(const bf16x8*)(ap + (size_t)mi * 512);
            al[mi] = *(const bf16x8*)(ap + 2048 + (size_t)mi * 512);
        }
        #pragma unroll
        for (int ni = 0; ni < 4; ++ni) {
            bh[ni] = *(const bf16x8*)(bp + (size_t)ni * 512);
            bl[ni] = *(const bf16x8*)(bp + 2048 + (size_t)ni * 512);
        }
        #pragma unroll
        for (int mi = 0; mi < 4; ++mi)
            #pragma unroll
            for (int ni = 0; ni < 4; ++ni) {
                acc[mi][ni] = __builtin_amdgcn_mfma_f32_16x16x32_bf16(ah[mi], bh[ni], acc[mi][ni], 0, 0, 0);
                acc[mi][ni] = __builtin_amdgcn_mfma_f32_16x16x32_bf16(ah[mi], bl[ni], acc[mi][ni], 0, 0, 0);
                acc[mi][ni] = __builtin_amdgcn_mfma_f32_16x16x32_bf16(al[mi], bh[ni], acc[mi][ni], 0, 0, 0);
            }
    }

    // epilogue (proven): row = kg*4 + reg, col = l16
    int m0 = mt * 128, n0 = nt * 128;
    #pragma unroll
    for (int mi = 0; mi < 4; ++mi)
        #pragma unroll
        for (int ni = 0; ni < 4; ++ni)
            #pragma unroll
            for (int r = 0; r < 4; ++r) {
                int m = m0 + wm * 64 + mi * 16 + kg * 4 + r;
                if (m < BP) {
                    int n = n0 + wn * 64 + ni * 16 + l16;
                    part[((size_t)kz * BP + m) * FOUT + n] = acc[mi][ni][r];
                }
            }
}

// ---------------- MLP + softmax + fused loss (r9-proven, unchanged) ----------------
__global__ __launch_bounds__(512) void mlp2x_loss(
    const float* __restrict__ part,
    const float* __restrict__ bfeat,
    const float* __restrict__ W1, const float* __restrict__ b1,
    const float* __restrict__ W2, const float* __restrict__ b2,
    const int* __restrict__ grade,
    float* __restrict__ probs, float* __restrict__ out0)
{
    __shared__ float sf[2][FOUT];
    __shared__ float shp[4][2][HID];
    __shared__ float sh[2][HID];
    __shared__ float sl[2][NG];
    __shared__ float sden[512];
    int r0 = blockIdx.x * 2;
    int t = threadIdx.x;

    float dwt = 0.0f;
    if (t < BP) {
        int g = grade[t];
        dwt = (g == 0) ? 1.0f : (g == 1 ? 2.0f : 4.0f);
    }
    sden[t] = dwt;

    for (int i = t; i < 2 * FOUT; i += 512) {
        int r = i / FOUT, c = i - r * FOUT;
        size_t base = (size_t)(r0 + r) * FOUT + c;
        float v = bfeat[c];
        #pragma unroll
        for (int kzi = 0; kzi < KSPL; ++kzi)
            v += part[(size_t)kzi * BP * FOUT + base];
        sf[r][c] = v;
    }
    __syncthreads();
    for (int s = 256; s > 0; s >>= 1) {
        if (t < s) sden[t] += sden[t + s];
        __syncthreads();
    }
    float den = sden[0];

    {
        int kq = t >> 7, j = t & 127;
        float a0 = (kq == 0) ? b1[j] : 0.0f, a1 = 0.0f;
        const float* wp = W1 + (size_t)(kq * 320) * HID + j;
        const float* s0 = &sf[0][kq * 320];
        const float* s1 = &sf[1][kq * 320];
        #pragma unroll 8
        for (int k = 0; k < 320; ++k) {
            float wv = wp[(size_t)k * HID];
            a0 = fmaf(s0[k], wv, a0);
            a1 = fmaf(s1[k], wv, a1);
        }
        shp[kq][0][j] = a0;
        shp[kq][1][j] = a1;
    }
    __syncthreads();
    if (t < 256) {
        int rr = t >> 7, j = t & 127;
        sh[rr][j] = fmaxf(shp[0][rr][j] + shp[1][rr][j] + shp[2][rr][j] + shp[3][rr][j], 0.0f);
    }
    __syncthreads();
    if (t < 6) {
        int rr = t / 3, c = t - rr * 3;
        float a = b2[c];
        #pragma unroll 16
        for (int k = 0; k < HID; ++k) a = fmaf(sh[rr][k], W2[k * NG + c], a);
        sl[rr][c] = a;
    }
    __syncthreads();
    if (t < 2) {
        float l0 = sl[t][0], l1 = sl[t][1], l2 = sl[t][2];
        float m = fmaxf(l0, fmaxf(l1, l2));
        float e0 = expf(l0 - m), e1 = expf(l1 - m), e2 = expf(l2 - m);
        float inv = 1.0f / (e0 + e1 + e2);
        int row = r0 + t;
        probs[row * NG + 0] = e0 * inv;
        probs[row * NG + 1] = e1 * inv;
        probs[row * NG + 2] = e2 * inv;

        int g = grade[row];
        float lv = (g == 0) ? l0 : (g == 1 ? l1 : l2);
        lv = fminf(fmaxf(lv, 1e-5f), 1.0f - 1e-5f);
        float wt = (g == 0) ? 1.0f : (g == 1 ? 2.0f : 4.0f);
        atomicAdd(out0, -(wt * logf(lv)) / den);
    }
}

// ---------------- launch ----------------
extern "C" void kernel_launch(void* const* d_in, const int* in_sizes, int n_in,
                              void* d_out, int out_size, void* d_ws, size_t ws_size,
                              hipStream_t stream) {
    const float* images  = (const float*)d_in[0];
    const float* z_pred  = (const float*)d_in[1];
    const float* xy_pred = (const float*)d_in[2];
    const int*   grade   = (const int*)d_in[3];
    const float* W_feat  = (const float*)d_in[4];
    const float* b_feat  = (const float*)d_in[5];
    const float* W1      = (const float*)d_in[6];
    const float* b1      = (const float*)d_in[7];
    const float* W2      = (const float*)d_in[8];
    const float* b2      = (const float*)d_in[9];

    float* out = (float*)d_out;
    char* w = (char*)d_ws;
    ushort* APF  = (ushort*)(w + OFF_APF);
    ushort* WPF  = (ushort*)(w + OFF_WPF);
    float*  part = (float*)(w + OFF_PART);

    fused_prep<<<CROP_BLOCKS + 640, 256, 0, stream>>>(images, z_pred, xy_pred, W_feat,
                                                      APF, WPF);
    gemm_mfma<<<10 * 4 * KSPL, 256, 0, stream>>>(APF, WPF, part, out);
    mlp2x_loss<<<BP / 2, 512, 0, stream>>>(part, b_feat, W1, b1, W2, b2, grade, out + 1, out);
}

// Round 17
// 66.813 us; speedup vs baseline: 2.2490x; 1.0419x over previous
//
#include <hip/hip_runtime.h>
#include <hip/hip_bf16.h>
#include <math.h>

#define B_    16
#define P_    25
#define D_SL_ 32
#define H_    320
#define W_    320
#define BP    400
#define KPIX  4096
#define FOUT  1280
#define HID   128
#define NG    3

#define M_PAD    512
#define KSPL     16
#define CH_STEPS 8           // 32-wide k-steps per k-chunk (256 k per chunk)

#define CROP_BLOCKS 512      // fused_prep: blocks [0,512) crops, [512,1152) prep_w

typedef __attribute__((ext_vector_type(8))) short  bf16x8;
typedef __attribute__((ext_vector_type(8))) ushort u16x8;
typedef __attribute__((ext_vector_type(4))) float  f32x4;
typedef unsigned long long ull;

// ws byte offsets
#define OFF_APF  0ull            // A frag-panel: 8.4 MB
#define OFF_WPF  8388608ull      // W frag-panel: 21 MB
#define OFF_PART 29360128ull     // 16 x 400 x 1280 x 4 = 32.8 MB -> ends 62.1 MB

// frag-panel index (16B units)  [r12-proven]:
//  A: ((((st*4+mt)*2+wm)*2+hl)*4+mi)*4+kg)*16 + l16   (hl stride = 256 idx16)
//  W: ((((st*10+nt)*2+wn)*2+hl)*4+ni)*4+kg)*16 + l16

__device__ inline void split_bf16(float x, ushort& hi, ushort& lo) {
    __hip_bfloat16 h = __float2bfloat16(x);
    float hf = __bfloat162float(h);
    __hip_bfloat16 l = __float2bfloat16(x - hf);
    hi = *(ushort*)&h;
    lo = *(ushort*)&l;
}

// ---------------- fused prep: crops->A-fragpanel + Wsum->W-fragpanel (r16-proven) ----
__global__ __launch_bounds__(256) void fused_prep(
    const float* __restrict__ images,
    const float* __restrict__ z_pred,
    const float* __restrict__ xy_pred,
    const float* __restrict__ Wf,
    ushort* __restrict__ APF, ushort* __restrict__ WPF)
{
    __shared__ float S[128][68];
    int t = threadIdx.x;

    if (blockIdx.x < CROP_BLOCKS) {
        int pt = blockIdx.x;
        int mt = pt >> 7, wmA = (pt >> 6) & 1, miA = (pt >> 4) & 3, l16A = pt & 15;

        if (pt >= BP) {
            u16x8 z8 = (u16x8)0;
            #pragma unroll
            for (int i = 0; i < 2; ++i) {
                int tau = t + i * 256;
                int st = tau >> 2, q = tau & 3;
                size_t base = (((((size_t)(st * 4 + mt) * 2 + wmA) * 2 + 0) * 4 + miA) * 4 + q) * 16 + l16A;
                *(u16x8*)(APF + base * 8) = z8;             // hi (hl=0)
                *(u16x8*)(APF + (base + 256) * 8) = z8;     // lo (hl=1)
            }
            return;
        }
        int b = pt / P_;
        int z = (int)rintf(z_pred[pt] - 1.0f);
        z = min(max(z, 0), D_SL_ - 1);
        int x = (int)rintf(4.0f * xy_pred[pt * 2 + 0]);
        int y = (int)rintf(4.0f * xy_pred[pt * 2 + 1]);
        x = min(max(x, 0), W_ - 1);
        y = min(max(y, 0), H_ - 1);
        const float* img = images + (size_t)(b * D_SL_ + z) * (H_ * W_);

        #pragma unroll
        for (int i = 0; i < 16; ++i) {
            int idx = t + i * 256;
            int r = idx >> 6, c = idx & 63;
            int iy = y - 32 + r, ix = x - 32 + c;
            float v = 0.0f;
            if ((unsigned)iy < (unsigned)H_ && (unsigned)ix < (unsigned)W_)
                v = img[iy * W_ + ix];
            S[r][c] = v;
        }
        __syncthreads();

        #pragma unroll
        for (int i = 0; i < 2; ++i) {
            int tau = t + i * 256;
            int st = tau >> 2, q = tau & 3;
            int r = st >> 1, cb = (st & 1) * 32 + q * 8;
            u16x8 vh, vl;
            #pragma unroll
            for (int e = 0; e < 8; ++e) {
                ushort hi, lo;
                split_bf16(S[r][cb + e], hi, lo);
                vh[e] = hi; vl[e] = lo;
            }
            size_t base = (((((size_t)(st * 4 + mt) * 2 + wmA) * 2 + 0) * 4 + miA) * 4 + q) * 16 + l16A;
            *(u16x8*)(APF + base * 8) = vh;
            *(u16x8*)(APF + (base + 256) * 8) = vl;
        }
        return;
    }

    // ---- W-prep: Wsum -> frag panel ----
    int wb = blockIdx.x - CROP_BLOCKS;   // 0..639
    int k0 = (wb & 31) * 128;
    int n0w = (wb >> 5) * 64;
    #pragma unroll
    for (int p = 0; p < 8; ++p) {
        int kl = p * 16 + (t >> 4);
        int nq = (t & 15) * 4;
        const float* base = Wf + (size_t)(k0 + kl) * FOUT + n0w + nq;
        float4 a = *(const float4*)base;
        float4 b = *(const float4*)(base + (size_t)KPIX * FOUT);
        float4 c = *(const float4*)(base + (size_t)2 * KPIX * FOUT);
        *(float4*)&S[kl][nq] = make_float4(a.x + b.x + c.x, a.y + b.y + c.y,
                                           a.z + b.z + c.z, a.w + b.w + c.w);
    }
    __syncthreads();
    int stepl = t >> 6;
    int nl = t & 63;
    int gstep = (wb & 31) * 4 + stepl;
    int n = n0w + nl;
    int nt = n >> 7, wnB = (n >> 6) & 1, niB = (n >> 4) & 3, l16B = n & 15;
    ushort hi[32], lo[32];
    #pragma unroll
    for (int j = 0; j < 32; ++j) {
        float v = S[stepl * 32 + j][nl];
        split_bf16(v, hi[j], lo[j]);
    }
    #pragma unroll
    for (int q = 0; q < 4; ++q) {
        u16x8 vh, vl;
        #pragma unroll
        for (int e = 0; e < 8; ++e) { vh[e] = hi[q * 8 + e]; vl[e] = lo[q * 8 + e]; }
        size_t base = (((((size_t)(gstep * 10 + nt) * 2 + wnB) * 2 + 0) * 4 + niB) * 4 + q) * 16 + l16B;
        *(u16x8*)(WPF + base * 8) = vh;
        *(u16x8*)(WPF + (base + 256) * 8) = vl;
    }
}

// ---------------- MFMA GEMM v7: LDS-free, KSPL=16 (640 blocks, 2.5 waves/SIMD) ----
// id = kz + 16*rr; rr -> (mt, nt). id%8 = kz%8 -> XCD pinning (kz,kz+8 share XCD).
__global__ __launch_bounds__(256) void gemm_mfma(
    const ushort* __restrict__ APF, const ushort* __restrict__ WPF,
    float* __restrict__ part, float* __restrict__ out0)
{
    int t = threadIdx.x;
    int id = blockIdx.x;
    int kz = id & 15;
    int rr_ = id >> 4;               // 0..39
    int nt = rr_ % 10;
    int mt = rr_ / 10;
    int stepbase = kz * CH_STEPS;

    if (id == 0 && t == 0) out0[0] = 0.0f;

    int w = t >> 6, l = t & 63;
    int wm = w & 1, wn = w >> 1;
    int l16 = l & 15, kg = l >> 4;

    f32x4 acc[4][4];
    #pragma unroll
    for (int i = 0; i < 4; ++i)
        #pragma unroll
        for (int j = 0; j < 4; ++j) acc[i][j] = (f32x4){0.f, 0.f, 0.f, 0.f};

    // per-lane base addresses (ushort units); strides: kg 128, mi/ni 512, hl 2048
    size_t abase0 = ((((size_t)mt * 2 + wm) * 2) * 16 + kg) * 16 + l16;
    abase0 *= 8;
    size_t bbase0 = ((((size_t)nt * 2 + wn) * 2) * 16 + kg) * 16 + l16;
    bbase0 *= 8;

    for (int s = 0; s < CH_STEPS; ++s) {
        int st = stepbase + s;
        const ushort* ap = APF + abase0 + (size_t)st * 32768;   // A st stride: 4096 idx16
        const ushort* bp = WPF + bbase0 + (size_t)st * 81920;   // W st stride: 10240 idx16

        bf16x8 ah[4], al[4], bh[4], bl[4];
        #pragma unroll
        for (int mi = 0; mi < 4; ++mi) {
            ah[mi] = *(const bf16x8*)(ap + (size_t)mi * 512);
            al[mi] = *(const bf16x8*)(ap + 2048 + (size_t)mi * 512);
        }
        #pragma unroll
        for (int ni = 0; ni < 4; ++ni) {
            bh[ni] = *(const bf16x8*)(bp + (size_t)ni * 512);
            bl[ni] = *(const bf16x8*)(bp + 2048 + (size_t)ni * 512);
        }
        #pragma unroll
        for (int mi = 0; mi < 4; ++mi)
            #pragma unroll
            for (int ni = 0; ni < 4; ++ni) {
                acc[mi][ni] = __builtin_amdgcn_mfma_f32_16x16x32_bf16(ah[mi], bh[ni], acc[mi][ni], 0, 0, 0);
                acc[mi][ni] = __builtin_amdgcn_mfma_f32_16x16x32_bf16(ah[mi], bl[ni], acc[mi][ni], 0, 0, 0);
                acc[mi][ni] = __builtin_amdgcn_mfma_f32_16x16x32_bf16(al[mi], bh[ni], acc[mi][ni], 0, 0, 0);
            }
    }

    // epilogue (proven): row = kg*4 + reg, col = l16
    int m0 = mt * 128, n0 = nt * 128;
    #pragma unroll
    for (int mi = 0; mi < 4; ++mi)
        #pragma unroll
        for (int ni = 0; ni < 4; ++ni)
            #pragma unroll
            for (int r = 0; r < 4; ++r) {
                int m = m0 + wm * 64 + mi * 16 + kg * 4 + r;
                if (m < BP) {
                    int n = n0 + wn * 64 + ni * 16 + l16;
                    part[((size_t)kz * BP + m) * FOUT + n] = acc[mi][ni][r];
                }
            }
}

// ---------------- MLP + softmax + fused loss (r9-proven; KSPL=16 reduce) ----------
__global__ __launch_bounds__(512) void mlp2x_loss(
    const float* __restrict__ part,
    const float* __restrict__ bfeat,
    const float* __restrict__ W1, const float* __restrict__ b1,
    const float* __restrict__ W2, const float* __restrict__ b2,
    const int* __restrict__ grade,
    float* __restrict__ probs, float* __restrict__ out0)
{
    __shared__ float sf[2][FOUT];
    __shared__ float shp[4][2][HID];
    __shared__ float sh[2][HID];
    __shared__ float sl[2][NG];
    __shared__ float sden[512];
    int r0 = blockIdx.x * 2;
    int t = threadIdx.x;

    float dwt = 0.0f;
    if (t < BP) {
        int g = grade[t];
        dwt = (g == 0) ? 1.0f : (g == 1 ? 2.0f : 4.0f);
    }
    sden[t] = dwt;

    for (int i = t; i < 2 * FOUT; i += 512) {
        int r = i / FOUT, c = i - r * FOUT;
        size_t base = (size_t)(r0 + r) * FOUT + c;
        float v = bfeat[c];
        #pragma unroll
        for (int kzi = 0; kzi < KSPL; ++kzi)
            v += part[(size_t)kzi * BP * FOUT + base];
        sf[r][c] = v;
    }
    __syncthreads();
    for (int s = 256; s > 0; s >>= 1) {
        if (t < s) sden[t] += sden[t + s];
        __syncthreads();
    }
    float den = sden[0];

    {
        int kq = t >> 7, j = t & 127;
        float a0 = (kq == 0) ? b1[j] : 0.0f, a1 = 0.0f;
        const float* wp = W1 + (size_t)(kq * 320) * HID + j;
        const float* s0 = &sf[0][kq * 320];
        const float* s1 = &sf[1][kq * 320];
        #pragma unroll 8
        for (int k = 0; k < 320; ++k) {
            float wv = wp[(size_t)k * HID];
            a0 = fmaf(s0[k], wv, a0);
            a1 = fmaf(s1[k], wv, a1);
        }
        shp[kq][0][j] = a0;
        shp[kq][1][j] = a1;
    }
    __syncthreads();
    if (t < 256) {
        int rr = t >> 7, j = t & 127;
        sh[rr][j] = fmaxf(shp[0][rr][j] + shp[1][rr][j] + shp[2][rr][j] + shp[3][rr][j], 0.0f);
    }
    __syncthreads();
    if (t < 6) {
        int rr = t / 3, c = t - rr * 3;
        float a = b2[c];
        #pragma unroll 16
        for (int k = 0; k < HID; ++k) a = fmaf(sh[rr][k], W2[k * NG + c], a);
        sl[rr][c] = a;
    }
    __syncthreads();
    if (t < 2) {
        float l0 = sl[t][0], l1 = sl[t][1], l2 = sl[t][2];
        float m = fmaxf(l0, fmaxf(l1, l2));
        float e0 = expf(l0 - m), e1 = expf(l1 - m), e2 = expf(l2 - m);
        float inv = 1.0f / (e0 + e1 + e2);
        int row = r0 + t;
        probs[row * NG + 0] = e0 * inv;
        probs[row * NG + 1] = e1 * inv;
        probs[row * NG + 2] = e2 * inv;

        int g = grade[row];
        float lv = (g == 0) ? l0 : (g == 1 ? l1 : l2);
        lv = fminf(fmaxf(lv, 1e-5f), 1.0f - 1e-5f);
        float wt = (g == 0) ? 1.0f : (g == 1 ? 2.0f : 4.0f);
        atomicAdd(out0, -(wt * logf(lv)) / den);
    }
}

// ---------------- launch ----------------
extern "C" void kernel_launch(void* const* d_in, const int* in_sizes, int n_in,
                              void* d_out, int out_size, void* d_ws, size_t ws_size,
                              hipStream_t stream) {
    const float* images  = (const float*)d_in[0];
    const float* z_pred  = (const float*)d_in[1];
    const float* xy_pred = (const float*)d_in[2];
    const int*   grade   = (const int*)d_in[3];
    const float* W_feat  = (const float*)d_in[4];
    const float* b_feat  = (const float*)d_in[5];
    const float* W1      = (const float*)d_in[6];
    const float* b1      = (const float*)d_in[7];
    const float* W2      = (const float*)d_in[8];
    const float* b2      = (const float*)d_in[9];

    float* out = (float*)d_out;
    char* w = (char*)d_ws;
    ushort* APF  = (ushort*)(w + OFF_APF);
    ushort* WPF  = (ushort*)(w + OFF_WPF);
    float*  part = (float*)(w + OFF_PART);

    fused_prep<<<CROP_BLOCKS + 640, 256, 0, stream>>>(images, z_pred, xy_pred, W_feat,
                                                      APF, WPF);
    gemm_mfma<<<10 * 4 * KSPL, 256, 0, stream>>>(APF, WPF, part, out);
    mlp2x_loss<<<BP / 2, 512, 0, stream>>>(part, b_feat, W1, b1, W2, b2, grade, out + 1, out);
}